// Round 4
// baseline (265.588 us; speedup 1.0000x reference)
//
#include <hip/hip_runtime.h>
#include <stdint.h>

#define B_ 4
#define S_ 2048
#define D_ 1024
#define H_ 16
#define DH_ 64
#define M_TOT (B_*S_)   // 8192
#define N1_ (3*D_)      // 3072
#define K_ D_           // 1024
#define NCH 16          // s-chunks for attention score partials
#define SCH 8           // s-chunks for attn_out

typedef __bf16 bf16_8 __attribute__((ext_vector_type(8)));
typedef float  f32x4  __attribute__((ext_vector_type(4)));

typedef __attribute__((address_space(1))) const void* gas_t;
typedef __attribute__((address_space(3))) void*       las_t;

__device__ __forceinline__ unsigned short f2bf(float f) {
    union { float f; unsigned u; } v; v.f = f;
    unsigned r = v.u + 0x7FFFu + ((v.u >> 16) & 1u);
    return (unsigned short)(r >> 16);
}

__device__ __forceinline__ void async_ld16(const void* g, void* l) {
    __builtin_amdgcn_global_load_lds((gas_t)g, (las_t)l, 16, 0, 0);
}

// ---------------- cast fp32 -> bf16 (X, W1, W2) ----------------
__global__ __launch_bounds__(256)
void cast_kernel(const float* __restrict__ X, const float* __restrict__ W1,
                 const float* __restrict__ W2, unsigned short* __restrict__ Xb,
                 unsigned short* __restrict__ W1b, unsigned short* __restrict__ W2b) {
    const int nX  = (M_TOT * K_) / 4;   // 2097152
    const int nW1 = (N1_ * K_) / 4;     // 786432
    int i = blockIdx.x * 256 + threadIdx.x;   // float4 index
    const float4* src; unsigned short* dst; int j;
    if (i < nX)            { src = (const float4*)X;  dst = Xb;  j = i; }
    else if (i < nX + nW1) { src = (const float4*)W1; dst = W1b; j = i - nX; }
    else                   { src = (const float4*)W2; dst = W2b; j = i - nX - nW1; }
    float4 v = src[j];
    ushort4 o;
    o.x = f2bf(v.x); o.y = f2bf(v.y); o.z = f2bf(v.z); o.w = f2bf(v.w);
    ((ushort4*)dst)[j] = o;
}

// ---------------- gemm_qkv: Y = X*W1^T + b1, split epilogue ----------------
// Q,K thirds stored TRANSPOSED per head: Qt/Kt[bh=b*16+h][d][s] (bf16).
// V third stored row-major: Vb[s_global][e=h*64+dh] (bf16, stride 1024).
// 128x128 tile, BK=64, global_load_lds w16, XOR-swizzled LDS (conflict-free).
__global__ __launch_bounds__(256)
void gemm_qkv(const unsigned short* __restrict__ A,
              const unsigned short* __restrict__ Bm,
              const float* __restrict__ bias,
              unsigned short* __restrict__ Qt, unsigned short* __restrict__ Kt,
              unsigned short* __restrict__ Vb) {
    __shared__ unsigned short As[128 * 64];
    __shared__ unsigned short Bs[128 * 64];
    const int t    = threadIdx.x;
    const int wid  = t >> 6;
    const int lane = t & 63;
    const int lrow = lane & 15;
    const int lq   = lane >> 4;
    const int m0   = blockIdx.y * 128;
    const int n0   = blockIdx.x * 128;
    const int wm   = (wid >> 1) * 64;
    const int wn   = (wid & 1) * 64;

    f32x4 acc[4][4] = {};

    for (int k0 = 0; k0 < K_; k0 += 64) {
#pragma unroll
        for (int p = 0; p < 4; p++) {
            const int c   = p * 256 + t;
            const int row = c >> 3;
            const int kb  = (c & 7) ^ (row & 7);
            async_ld16(A  + (size_t)(m0 + row) * K_ + k0 + kb * 8, (char*)As + c * 16);
            async_ld16(Bm + (size_t)(n0 + row) * K_ + k0 + kb * 8, (char*)Bs + c * 16);
        }
        __syncthreads();
#pragma unroll
        for (int ks = 0; ks < 2; ks++) {
            bf16_8 af[4], bfr[4];
#pragma unroll
            for (int mt = 0; mt < 4; mt++) {
                const int r  = wm + mt * 16 + lrow;
                const int kb = (ks * 4 + lq) ^ (r & 7);
                af[mt] = *(const bf16_8*)(As + (r * 8 + kb) * 8);
            }
#pragma unroll
            for (int nt = 0; nt < 4; nt++) {
                const int r  = wn + nt * 16 + lrow;
                const int kb = (ks * 4 + lq) ^ (r & 7);
                bfr[nt] = *(const bf16_8*)(Bs + (r * 8 + kb) * 8);
            }
#pragma unroll
            for (int mt = 0; mt < 4; mt++)
#pragma unroll
                for (int nt = 0; nt < 4; nt++)
                    acc[mt][nt] = __builtin_amdgcn_mfma_f32_16x16x32_bf16(af[mt], bfr[nt], acc[mt][nt], 0, 0, 0);
        }
        __syncthreads();
    }

    const int third = n0 >> 10;         // 0=Q, 1=K, 2=V (block-uniform)
    if (third < 2) {
        unsigned short* T = third ? Kt : Qt;
#pragma unroll
        for (int nt = 0; nt < 4; nt++) {
            const int gcol = n0 + wn + nt * 16 + lrow;
            const float bv = bias[gcol];
            const int col  = gcol & 1023;          // within third
            const int hh = col >> 6, d = col & 63;
#pragma unroll
            for (int mt = 0; mt < 4; mt++) {
                const int row = m0 + wm + mt * 16 + lq * 4;   // global s-row
                const int bb = row >> 11, s = row & 2047;
                f32x4 a = acc[mt][nt];
                ushort4 o;
                o.x = f2bf(a[0] + bv); o.y = f2bf(a[1] + bv);
                o.z = f2bf(a[2] + bv); o.w = f2bf(a[3] + bv);
                *(ushort4*)(T + ((size_t)((bb * 16 + hh) * 64 + d)) * 2048 + s) = o;
            }
        }
    } else {
#pragma unroll
        for (int nt = 0; nt < 4; nt++) {
            const int gcol = n0 + wn + nt * 16 + lrow;
            const float bv = bias[gcol];
            const int col  = gcol & 1023;
#pragma unroll
            for (int mt = 0; mt < 4; mt++) {
                const int row = m0 + wm + mt * 16 + lq * 4;
                f32x4 a = acc[mt][nt];
#pragma unroll
                for (int i = 0; i < 4; i++)
                    Vb[(size_t)(row + i) * 1024 + col] = f2bf(a[i] + bv);
            }
        }
    }
}

// ---------------- gemm_bt: C[M,N] = A[M,K] * B[N,K]^T + bias (fp32 out) ---
__global__ __launch_bounds__(256)
void gemm_bt(const unsigned short* __restrict__ A,
             const unsigned short* __restrict__ Bm,
             const float* __restrict__ bias,
             float* __restrict__ C, int K, int N) {
    __shared__ unsigned short As[128 * 64];
    __shared__ unsigned short Bs[128 * 64];
    const int t    = threadIdx.x;
    const int wid  = t >> 6;
    const int lane = t & 63;
    const int lrow = lane & 15;
    const int lq   = lane >> 4;
    const int m0   = blockIdx.y * 128;
    const int n0   = blockIdx.x * 128;
    const int wm   = (wid >> 1) * 64;
    const int wn   = (wid & 1) * 64;

    f32x4 acc[4][4] = {};

    for (int k0 = 0; k0 < K; k0 += 64) {
#pragma unroll
        for (int p = 0; p < 4; p++) {
            const int c   = p * 256 + t;
            const int row = c >> 3;
            const int kb  = (c & 7) ^ (row & 7);
            async_ld16(A  + (size_t)(m0 + row) * K + k0 + kb * 8, (char*)As + c * 16);
            async_ld16(Bm + (size_t)(n0 + row) * K + k0 + kb * 8, (char*)Bs + c * 16);
        }
        __syncthreads();
#pragma unroll
        for (int ks = 0; ks < 2; ks++) {
            bf16_8 af[4], bfr[4];
#pragma unroll
            for (int mt = 0; mt < 4; mt++) {
                const int r  = wm + mt * 16 + lrow;
                const int kb = (ks * 4 + lq) ^ (r & 7);
                af[mt] = *(const bf16_8*)(As + (r * 8 + kb) * 8);
            }
#pragma unroll
            for (int nt = 0; nt < 4; nt++) {
                const int r  = wn + nt * 16 + lrow;
                const int kb = (ks * 4 + lq) ^ (r & 7);
                bfr[nt] = *(const bf16_8*)(Bs + (r * 8 + kb) * 8);
            }
#pragma unroll
            for (int mt = 0; mt < 4; mt++)
#pragma unroll
                for (int nt = 0; nt < 4; nt++)
                    acc[mt][nt] = __builtin_amdgcn_mfma_f32_16x16x32_bf16(af[mt], bfr[nt], acc[mt][nt], 0, 0, 0);
        }
        __syncthreads();
    }

#pragma unroll
    for (int nt = 0; nt < 4; nt++) {
        const int col = n0 + wn + nt * 16 + lrow;
        const float bv = bias[col];
#pragma unroll
        for (int mt = 0; mt < 4; mt++) {
            const int row = m0 + wm + mt * 16 + lq * 4;
            f32x4 a = acc[mt][nt];
#pragma unroll
            for (int i = 0; i < 4; i++)
                C[(size_t)(row + i) * N + col] = a[i] + bv;
        }
    }
}

// ---------------- attention, stage 1: partial scores (mini-gemm) ----------
// grid (bh=64, ch=NCH). partial[d][e] = sum_{s in chunk} Qt[bh,d,s]*Kt[bh,e,s]
// Both operands s(=k)-contiguous -> global_load_lds + XOR swizzle, no transpose.
__global__ __launch_bounds__(256)
void attn_scores(const unsigned short* __restrict__ Qt,
                 const unsigned short* __restrict__ Kt,
                 float* __restrict__ Scp) {
    __shared__ unsigned short Qs[64 * 64];
    __shared__ unsigned short Ks[64 * 64];
    const int bh = blockIdx.x, ch = blockIdx.y;
    const int t = threadIdx.x, wid = t >> 6, lane = t & 63;
    const int lrow = lane & 15, lq = lane >> 4;
    const size_t qb = (size_t)bh * 64 * 2048;
    const int kbase = ch * (S_ / NCH);   // 128 per chunk

    f32x4 acc[4] = {};
    for (int k0 = 0; k0 < S_ / NCH; k0 += 64) {
#pragma unroll
        for (int p = 0; p < 2; p++) {
            const int c   = p * 256 + t;          // chunk 0..511
            const int row = c >> 3;
            const int kb  = (c & 7) ^ (row & 7);
            const size_t off = qb + (size_t)row * 2048 + kbase + k0 + kb * 8;
            async_ld16(Qt + off, (char*)Qs + c * 16);
            async_ld16(Kt + off, (char*)Ks + c * 16);
        }
        __syncthreads();
#pragma unroll
        for (int ks = 0; ks < 2; ks++) {
            const int rA  = wid * 16 + lrow;
            const int kbA = (ks * 4 + lq) ^ (rA & 7);
            bf16_8 aq = *(const bf16_8*)(Qs + (rA * 8 + kbA) * 8);
#pragma unroll
            for (int nt = 0; nt < 4; nt++) {
                const int rB  = nt * 16 + lrow;
                const int kbB = (ks * 4 + lq) ^ (rB & 7);
                bf16_8 bk = *(const bf16_8*)(Ks + (rB * 8 + kbB) * 8);
                acc[nt] = __builtin_amdgcn_mfma_f32_16x16x32_bf16(aq, bk, acc[nt], 0, 0, 0);
            }
        }
        __syncthreads();
    }

    float* out = Scp + (size_t)(bh * NCH + ch) * 64 * 64;
#pragma unroll
    for (int nt = 0; nt < 4; nt++)
#pragma unroll
        for (int i = 0; i < 4; i++)
            out[(wid * 16 + lq * 4 + i) * 64 + nt * 16 + lrow] = acc[nt][i];
}

// ---------------- attention, stage 2: reduce partials + softmax ----------------
__global__ __launch_bounds__(256)
void attn_softmax(const float* __restrict__ Scp, unsigned short* __restrict__ Wb) {
    const int bh = blockIdx.x;
    const int t = threadIdx.x;
    const int d = t >> 2, q = t & 3;
    float s[16] = {};
#pragma unroll
    for (int c = 0; c < NCH; c++) {
        const float4* p = (const float4*)(Scp + ((size_t)(bh * NCH + c) * 64 + d) * 64 + q * 16);
#pragma unroll
        for (int j = 0; j < 4; j++) {
            float4 v = p[j];
            s[j*4+0] += v.x; s[j*4+1] += v.y; s[j*4+2] += v.z; s[j*4+3] += v.w;
        }
    }
    const float scale = 0.022097086912079608f;  // 1/sqrt(2048)
    float m = -3.0e38f;
#pragma unroll
    for (int i = 0; i < 16; i++) { s[i] *= scale; m = fmaxf(m, s[i]); }
    m = fmaxf(m, __shfl_xor(m, 1));
    m = fmaxf(m, __shfl_xor(m, 2));
    float sum = 0.f;
#pragma unroll
    for (int i = 0; i < 16; i++) { s[i] = __expf(s[i] - m); sum += s[i]; }
    sum += __shfl_xor(sum, 1);
    sum += __shfl_xor(sum, 2);
    const float inv = 1.0f / sum;
    unsigned short* w = Wb + (size_t)bh * 4096 + d * 64 + q * 16;
    ushort4 o0, o1, o2, o3;
    o0.x=f2bf(s[0]*inv);  o0.y=f2bf(s[1]*inv);  o0.z=f2bf(s[2]*inv);  o0.w=f2bf(s[3]*inv);
    o1.x=f2bf(s[4]*inv);  o1.y=f2bf(s[5]*inv);  o1.z=f2bf(s[6]*inv);  o1.w=f2bf(s[7]*inv);
    o2.x=f2bf(s[8]*inv);  o2.y=f2bf(s[9]*inv);  o2.z=f2bf(s[10]*inv); o2.w=f2bf(s[11]*inv);
    o3.x=f2bf(s[12]*inv); o3.y=f2bf(s[13]*inv); o3.z=f2bf(s[14]*inv); o3.w=f2bf(s[15]*inv);
    ((ushort4*)w)[0]=o0; ((ushort4*)w)[1]=o1; ((ushort4*)w)[2]=o2; ((ushort4*)w)[3]=o3;
}

// ---------------- attention, stage 3: O = w @ V^T ----------------
// grid (bh=64, sc=SCH). O[b,h,d,s] = sum_e w[d][e] * Vb[s][h*64+e], flat [B,H,DH,S].
__global__ __launch_bounds__(256)
void attn_out(const unsigned short* __restrict__ Vb, const unsigned short* __restrict__ Wb,
              unsigned short* __restrict__ O) {
    __shared__ unsigned short Ws[64 * 72];
    const int bh = blockIdx.x, sc = blockIdx.y;
    const int b = bh >> 4, h = bh & 15;
    const int voff = h * 64;
    const int t = threadIdx.x, wid = t >> 6, lane = t & 63;
    const int lrow = lane & 15, lq = lane >> 4;

    {
        const int d = t >> 2, q = t & 3;
        const uint4* src = (const uint4*)(Wb + (size_t)bh * 4096 + d * 64 + q * 16);
        uint4* dst = (uint4*)(Ws + d * 72 + q * 16);
        dst[0] = src[0];
        *(uint4*)(Ws + d * 72 + q * 16 + 8) = src[1];
    }
    __syncthreads();

    bf16_8 aw[4][2];
#pragma unroll
    for (int mt = 0; mt < 4; mt++)
#pragma unroll
        for (int ks = 0; ks < 2; ks++)
            aw[mt][ks] = *(const bf16_8*)(Ws + (mt * 16 + lrow) * 72 + ks * 32 + lq * 8);

    const size_t vbase = (size_t)b * S_ * 1024;
    const size_t obase = (size_t)b * (H_ * DH_ * S_) + (size_t)h * (DH_ * S_);
    const int s0 = sc * 256 + wid * 64;
    f32x4 o[4][4] = {};
#pragma unroll
    for (int ks = 0; ks < 2; ks++) {
        bf16_8 bv[4];
#pragma unroll
        for (int nt = 0; nt < 4; nt++)
            bv[nt] = *(const bf16_8*)(Vb + vbase + (size_t)(s0 + nt * 16 + lrow) * 1024 + voff + ks * 32 + lq * 8);
#pragma unroll
        for (int mt = 0; mt < 4; mt++)
#pragma unroll
            for (int nt = 0; nt < 4; nt++)
                o[mt][nt] = __builtin_amdgcn_mfma_f32_16x16x32_bf16(aw[mt][ks], bv[nt], o[mt][nt], 0, 0, 0);
    }
#pragma unroll
    for (int mt = 0; mt < 4; mt++)
#pragma unroll
        for (int nt = 0; nt < 4; nt++) {
            const int d = mt * 16 + lq * 4;
            const int s = s0 + nt * 16 + lrow;
#pragma unroll
            for (int i = 0; i < 4; i++)
                O[obase + (size_t)(d + i) * S_ + s] = f2bf(o[mt][nt][i]);
        }
}

extern "C" void kernel_launch(void* const* d_in, const int* in_sizes, int n_in,
                              void* d_out, int out_size, void* d_ws, size_t ws_size,
                              hipStream_t stream) {
    const float* X  = (const float*)d_in[0];
    const float* W1 = (const float*)d_in[1];
    const float* b1 = (const float*)d_in[2];
    const float* W2 = (const float*)d_in[3];
    const float* b2 = (const float*)d_in[4];

    char* ws = (char*)d_ws;
    unsigned short* Xb  = (unsigned short*)(ws + 0);                 // 16 MB, dead after GEMM1
    unsigned short* W1b = (unsigned short*)(ws + (16u << 20));       // 6 MB, dead after GEMM1
    unsigned short* W2b = (unsigned short*)(ws + (22u << 20));       // 2 MB
    unsigned short* Qt  = (unsigned short*)(ws + (24u << 20));       // 16 MB [bh][d][s]
    unsigned short* Kt  = (unsigned short*)(ws + (40u << 20));       // 16 MB [bh][d][s]
    unsigned short* Vb  = (unsigned short*)(ws + (56u << 20));       // 16 MB [s][e]
    // after GEMM1, [0,22MB) is free:
    unsigned short* Wb  = (unsigned short*)(ws + 0);                 // 512 KB softmaxed weights
    unsigned short* Ob  = (unsigned short*)(ws + (1u << 20));        // 16 MB attention output
    // d_out (32 MB fp32) is dead until GEMM2 -> use 16.8 MB for score partials
    float* Scp = (float*)d_out;

    cast_kernel<<<12288, 256, 0, stream>>>(X, W1, W2, Xb, W1b, W2b);
    gemm_qkv<<<dim3(N1_ / 128, M_TOT / 128), 256, 0, stream>>>(Xb, W1b, b1, Qt, Kt, Vb);
    attn_scores<<<dim3(64, NCH), 256, 0, stream>>>(Qt, Kt, Scp);
    attn_softmax<<<64, 256, 0, stream>>>(Scp, Wb);
    attn_out<<<dim3(64, SCH), 256, 0, stream>>>(Vb, Wb, Ob);
    gemm_bt<<<dim3(D_ / 128, M_TOT / 128), 256, 0, stream>>>(Ob, W2b, b2, (float*)d_out, K_, D_);
}

// Round 5
// 211.889 us; speedup vs baseline: 1.2534x; 1.2534x over previous
//
#include <hip/hip_runtime.h>
#include <stdint.h>

#define B_ 4
#define S_ 2048
#define D_ 1024
#define H_ 16
#define DH_ 64
#define M_TOT (B_*S_)   // 8192
#define N1_ (3*D_)      // 3072
#define K_ D_           // 1024
#define NCH 8           // s-chunks for attention score partials

typedef __bf16 bf16_8 __attribute__((ext_vector_type(8)));
typedef float  f32x4  __attribute__((ext_vector_type(4)));

typedef __attribute__((address_space(1))) const void* gas_t;
typedef __attribute__((address_space(3))) void*       las_t;

__device__ __forceinline__ unsigned short f2bf(float f) {
    union { float f; unsigned u; } v; v.f = f;
    unsigned r = v.u + 0x7FFFu + ((v.u >> 16) & 1u);
    return (unsigned short)(r >> 16);
}

__device__ __forceinline__ void async_ld16(const void* g, void* l) {
    __builtin_amdgcn_global_load_lds((gas_t)g, (las_t)l, 16, 0, 0);
}

// ---------------- cast fp32 -> bf16 (X, W1, W2) ----------------
__global__ __launch_bounds__(256)
void cast_kernel(const float* __restrict__ X, const float* __restrict__ W1,
                 const float* __restrict__ W2, unsigned short* __restrict__ Xb,
                 unsigned short* __restrict__ W1b, unsigned short* __restrict__ W2b) {
    const int nX  = (M_TOT * K_) / 4;   // 2097152
    const int nW1 = (N1_ * K_) / 4;     // 786432
    int i = blockIdx.x * 256 + threadIdx.x;   // float4 index
    const float4* src; unsigned short* dst; int j;
    if (i < nX)            { src = (const float4*)X;  dst = Xb;  j = i; }
    else if (i < nX + nW1) { src = (const float4*)W1; dst = W1b; j = i - nX; }
    else                   { src = (const float4*)W2; dst = W2b; j = i - nX - nW1; }
    float4 v = src[j];
    ushort4 o;
    o.x = f2bf(v.x); o.y = f2bf(v.y); o.z = f2bf(v.z); o.w = f2bf(v.w);
    ((ushort4*)dst)[j] = o;
}

// ---------------- gemm_bt: C[M,N] = A[M,K] * B[N,K]^T + bias ----------------
// 128x128 tile, 4 waves (2x2), BK=64, global_load_lds width 16,
// XOR-swizzled LDS (conflict-free), XCD-aware block swizzle:
// linear id -> xcd = lid&7; each XCD owns a contiguous 8-row M-stripe so its
// A-panels (8 x 256 KB) stay L2-resident while B streams.
template<int N, int NBX, bool OUT_BF16>
__global__ __launch_bounds__(256)
void gemm_bt(const unsigned short* __restrict__ A,
             const unsigned short* __restrict__ Bm,
             const float* __restrict__ bias,
             void* __restrict__ C, int K) {
    __shared__ unsigned short As[128 * 64];
    __shared__ unsigned short Bs[128 * 64];
    const int t    = threadIdx.x;
    const int wid  = t >> 6;
    const int lane = t & 63;
    const int lrow = lane & 15;
    const int lq   = lane >> 4;

    const int lid  = blockIdx.y * NBX + blockIdx.x;
    const int xcd  = lid & 7;
    const int slot = lid >> 3;
    const int by   = xcd * (gridDim.y >> 3) + slot / NBX;
    const int bx   = slot % NBX;
    const int m0   = by * 128;
    const int n0   = bx * 128;

    const int wm   = (wid >> 1) * 64;
    const int wn   = (wid & 1) * 64;

    f32x4 acc[4][4] = {};

    for (int k0 = 0; k0 < K; k0 += 64) {
#pragma unroll
        for (int p = 0; p < 4; p++) {
            const int c   = p * 256 + t;          // chunk 0..1023
            const int row = c >> 3;
            const int kb  = (c & 7) ^ (row & 7);  // un-swizzled global k-block
            async_ld16(A  + (size_t)(m0 + row) * K + k0 + kb * 8, (char*)As + c * 16);
            async_ld16(Bm + (size_t)(n0 + row) * K + k0 + kb * 8, (char*)Bs + c * 16);
        }
        __syncthreads();

#pragma unroll
        for (int ks = 0; ks < 2; ks++) {
            bf16_8 af[4], bfr[4];
#pragma unroll
            for (int mt = 0; mt < 4; mt++) {
                const int r  = wm + mt * 16 + lrow;
                const int kb = (ks * 4 + lq) ^ (r & 7);
                af[mt] = *(const bf16_8*)(As + (r * 8 + kb) * 8);
            }
#pragma unroll
            for (int nt = 0; nt < 4; nt++) {
                const int r  = wn + nt * 16 + lrow;
                const int kb = (ks * 4 + lq) ^ (r & 7);
                bfr[nt] = *(const bf16_8*)(Bs + (r * 8 + kb) * 8);
            }
#pragma unroll
            for (int mt = 0; mt < 4; mt++)
#pragma unroll
                for (int nt = 0; nt < 4; nt++)
                    acc[mt][nt] = __builtin_amdgcn_mfma_f32_16x16x32_bf16(af[mt], bfr[nt], acc[mt][nt], 0, 0, 0);
        }
        __syncthreads();
    }

    // epilogue: C row = m0+wm+mt*16+lq*4+i, col = n0+wn+nt*16+lrow
#pragma unroll
    for (int nt = 0; nt < 4; nt++) {
        const int col = n0 + wn + nt * 16 + lrow;
        const float bv = bias[col];
#pragma unroll
        for (int mt = 0; mt < 4; mt++) {
            const int row = m0 + wm + mt * 16 + lq * 4;
            f32x4 a = acc[mt][nt];
            if (OUT_BF16) {
                unsigned short* Cp = (unsigned short*)C;
#pragma unroll
                for (int i = 0; i < 4; i++)
                    Cp[(size_t)(row + i) * N + col] = f2bf(a[i] + bv);
            } else {
                float* Cp = (float*)C;
#pragma unroll
                for (int i = 0; i < 4; i++)
                    Cp[(size_t)(row + i) * N + col] = a[i] + bv;
            }
        }
    }
}

// ---------------- attention, stage 1: partial scores ----------------
// grid (bh=64, chunk=NCH). Each block: partial[d][e] = sum_{s in chunk} Q[s][d]K[s][e]
// stored fp32 at Scp[((bh*NCH+ch)*64+d)*64+e]
__global__ __launch_bounds__(256)
void attn_scores(const unsigned short* __restrict__ Y, float* __restrict__ Scp) {
    __shared__ unsigned short Qs[64 * 72];
    __shared__ unsigned short Ks[64 * 72];
    const int bh = blockIdx.x, ch = blockIdx.y;
    const int b = bh >> 4, h = bh & 15;
    const size_t ybase = (size_t)b * S_ * 3072;
    const int qoff = h * 64, koff = D_ + h * 64;
    const int t = threadIdx.x, wid = t >> 6, lane = t & 63;
    const int lrow = lane & 15, lq = lane >> 4;

    f32x4 acc[4] = {};
    const int sbeg = ch * (S_ / NCH);
    for (int s0 = sbeg; s0 < sbeg + S_ / NCH; s0 += 64) {
#pragma unroll
        for (int p = 0; p < 4; p++) {
            int idx = p * 256 + t;            // 0..1023
            int r = idx >> 4, cg = (idx & 15) * 4;
            const size_t gb = ybase + (size_t)(s0 + r) * 3072;
            ushort4 q4 = *(const ushort4*)(Y + gb + qoff + cg);
            ushort4 k4 = *(const ushort4*)(Y + gb + koff + cg);
            Qs[(cg + 0) * 72 + r] = q4.x; Qs[(cg + 1) * 72 + r] = q4.y;
            Qs[(cg + 2) * 72 + r] = q4.z; Qs[(cg + 3) * 72 + r] = q4.w;
            Ks[(cg + 0) * 72 + r] = k4.x; Ks[(cg + 1) * 72 + r] = k4.y;
            Ks[(cg + 2) * 72 + r] = k4.z; Ks[(cg + 3) * 72 + r] = k4.w;
        }
        __syncthreads();
#pragma unroll
        for (int ks = 0; ks < 2; ks++) {
            bf16_8 aq = *(const bf16_8*)(Qs + (wid * 16 + lrow) * 72 + ks * 32 + lq * 8);
#pragma unroll
            for (int nt = 0; nt < 4; nt++) {
                bf16_8 bk = *(const bf16_8*)(Ks + (nt * 16 + lrow) * 72 + ks * 32 + lq * 8);
                acc[nt] = __builtin_amdgcn_mfma_f32_16x16x32_bf16(aq, bk, acc[nt], 0, 0, 0);
            }
        }
        __syncthreads();
    }

    float* out = Scp + (size_t)(bh * NCH + ch) * 64 * 64;
#pragma unroll
    for (int nt = 0; nt < 4; nt++)
#pragma unroll
        for (int i = 0; i < 4; i++)
            out[(wid * 16 + lq * 4 + i) * 64 + nt * 16 + lrow] = acc[nt][i];
}

// ---------------- attention, stage 2: reduce partials + softmax ----------------
__global__ __launch_bounds__(256)
void attn_softmax(const float* __restrict__ Scp, unsigned short* __restrict__ Wb) {
    const int bh = blockIdx.x;
    const int t = threadIdx.x;
    const int d = t >> 2, q = t & 3;
    float s[16] = {};
#pragma unroll
    for (int c = 0; c < NCH; c++) {
        const float4* p = (const float4*)(Scp + ((size_t)(bh * NCH + c) * 64 + d) * 64 + q * 16);
#pragma unroll
        for (int j = 0; j < 4; j++) {
            float4 v = p[j];
            s[j*4+0] += v.x; s[j*4+1] += v.y; s[j*4+2] += v.z; s[j*4+3] += v.w;
        }
    }
    const float scale = 0.022097086912079608f;  // 1/sqrt(2048)
    float m = -3.0e38f;
#pragma unroll
    for (int i = 0; i < 16; i++) { s[i] *= scale; m = fmaxf(m, s[i]); }
    m = fmaxf(m, __shfl_xor(m, 1));
    m = fmaxf(m, __shfl_xor(m, 2));
    float sum = 0.f;
#pragma unroll
    for (int i = 0; i < 16; i++) { s[i] = __expf(s[i] - m); sum += s[i]; }
    sum += __shfl_xor(sum, 1);
    sum += __shfl_xor(sum, 2);
    const float inv = 1.0f / sum;
    unsigned short* w = Wb + (size_t)bh * 4096 + d * 64 + q * 16;
    ushort4 o0, o1, o2, o3;
    o0.x=f2bf(s[0]*inv);  o0.y=f2bf(s[1]*inv);  o0.z=f2bf(s[2]*inv);  o0.w=f2bf(s[3]*inv);
    o1.x=f2bf(s[4]*inv);  o1.y=f2bf(s[5]*inv);  o1.z=f2bf(s[6]*inv);  o1.w=f2bf(s[7]*inv);
    o2.x=f2bf(s[8]*inv);  o2.y=f2bf(s[9]*inv);  o2.z=f2bf(s[10]*inv); o2.w=f2bf(s[11]*inv);
    o3.x=f2bf(s[12]*inv); o3.y=f2bf(s[13]*inv); o3.z=f2bf(s[14]*inv); o3.w=f2bf(s[15]*inv);
    ((ushort4*)w)[0]=o0; ((ushort4*)w)[1]=o1; ((ushort4*)w)[2]=o2; ((ushort4*)w)[3]=o3;
}

// ---------------- attention, stage 3: O = w @ V^T ----------------
// grid (bh=64, sc=8). Block covers 256 s-columns; wave wid covers 64 of them.
// O[b,h,d,s] = sum_e w[d][e] * V[s][e], flat [B,H,DH,S] bf16.
__global__ __launch_bounds__(256)
void attn_out(const unsigned short* __restrict__ Y, const unsigned short* __restrict__ Wb,
              unsigned short* __restrict__ O) {
    __shared__ unsigned short Ws[64 * 72];
    const int bh = blockIdx.x, sc = blockIdx.y;
    const int b = bh >> 4, h = bh & 15;
    const size_t ybase = (size_t)b * S_ * 3072;
    const int voff = 2 * D_ + h * 64;
    const int t = threadIdx.x, wid = t >> 6, lane = t & 63;
    const int lrow = lane & 15, lq = lane >> 4;

    {
        const int d = t >> 2, q = t & 3;
        const uint4* src = (const uint4*)(Wb + (size_t)bh * 4096 + d * 64 + q * 16);
        uint4* dst = (uint4*)(Ws + d * 72 + q * 16);
        dst[0] = src[0];
        *(uint4*)(Ws + d * 72 + q * 16 + 8) = src[1];
    }
    __syncthreads();

    bf16_8 aw[4][2];
#pragma unroll
    for (int mt = 0; mt < 4; mt++)
#pragma unroll
        for (int ks = 0; ks < 2; ks++)
            aw[mt][ks] = *(const bf16_8*)(Ws + (mt * 16 + lrow) * 72 + ks * 32 + lq * 8);

    const size_t obase = (size_t)b * (H_ * DH_ * S_) + (size_t)h * (DH_ * S_);
    const int s0 = sc * 256 + wid * 64;
    f32x4 o[4][4] = {};
#pragma unroll
    for (int ks = 0; ks < 2; ks++) {
        bf16_8 bv[4];
#pragma unroll
        for (int nt = 0; nt < 4; nt++)
            bv[nt] = *(const bf16_8*)(Y + ybase + (size_t)(s0 + nt * 16 + lrow) * 3072 + voff + ks * 32 + lq * 8);
#pragma unroll
        for (int mt = 0; mt < 4; mt++)
#pragma unroll
            for (int nt = 0; nt < 4; nt++)
                o[mt][nt] = __builtin_amdgcn_mfma_f32_16x16x32_bf16(aw[mt][ks], bv[nt], o[mt][nt], 0, 0, 0);
    }
#pragma unroll
    for (int mt = 0; mt < 4; mt++)
#pragma unroll
        for (int nt = 0; nt < 4; nt++) {
            const int d = mt * 16 + lq * 4;
            const int s = s0 + nt * 16 + lrow;
#pragma unroll
            for (int i = 0; i < 4; i++)
                O[obase + (size_t)(d + i) * S_ + s] = f2bf(o[mt][nt][i]);
        }
}

extern "C" void kernel_launch(void* const* d_in, const int* in_sizes, int n_in,
                              void* d_out, int out_size, void* d_ws, size_t ws_size,
                              hipStream_t stream) {
    const float* X  = (const float*)d_in[0];
    const float* W1 = (const float*)d_in[1];
    const float* b1 = (const float*)d_in[2];
    const float* W2 = (const float*)d_in[3];
    const float* b2 = (const float*)d_in[4];

    char* ws = (char*)d_ws;
    unsigned short* Xb  = (unsigned short*)(ws + 0);                 // 16 MB, dead after GEMM1
    unsigned short* W1b = (unsigned short*)(ws + (16u << 20));       // 6 MB, dead after GEMM1
    unsigned short* W2b = (unsigned short*)(ws + (22u << 20));       // 2 MB
    unsigned short* Yb  = (unsigned short*)(ws + (24u << 20));       // 48 MB
    // after GEMM1, [0,22MB) is free:
    unsigned short* Wb  = (unsigned short*)(ws + 0);                 // 512 KB softmaxed weights
    unsigned short* Ob  = (unsigned short*)(ws + (1u << 20));        // 16 MB attention output
    // d_out (32 MB fp32) is dead until GEMM2 -> use 8 MB of it for score partials
    float* Scp = (float*)d_out;

    cast_kernel<<<12288, 256, 0, stream>>>(X, W1, W2, Xb, W1b, W2b);
    gemm_bt<N1_, N1_/128, true><<<dim3(N1_ / 128, M_TOT / 128), 256, 0, stream>>>(Xb, W1b, b1, Yb, K_);
    attn_scores<<<dim3(64, NCH), 256, 0, stream>>>(Yb, Scp);
    attn_softmax<<<64, 256, 0, stream>>>(Scp, Wb);
    attn_out<<<dim3(64, NCH), 256, 0, stream>>>(Yb, Wb, Ob);
    gemm_bt<D_, D_/128, false><<<dim3(D_ / 128, M_TOT / 128), 256, 0, stream>>>(Ob, W2b, b2, d_out, K_);
}